// Round 8
// baseline (2527.840 us; speedup 1.0000x reference)
//
#include <hip/hip_runtime.h>
#include <hip/hip_bf16.h>

typedef __hip_bfloat16 bf16;

#define BBB 8
#define LL 2048
#define DDD 512
#define II 256
#define SS 8
#define MM (BBB*LL)      // 16384 rows

// ---- workspace regions (bytes), total 121,634,816 <= ws_size (>=121,634,820 proven R6) ----
#define WS_SI    0l          // si    bf16 [M,512]        ->  16,777,216
#define WS_U0    16777216l   // u0    bf16 [M,512] (y0|zb0) -> 33,554,432
#define WS_U1    33554432l   // u1    bf16 [M,512] (y1|zb1) -> 50,331,648
#define WS_XZ    50331648l   // xz    bf16 [M,1024]       ->  83,886,080
#define WS_FWD   50331648l   // fwd   bf16 [M,512] (alias xz, after conv)
#define WS_BWD   67108864l   // bwd   bf16 [M,512] (alias xz, after conv)
#define WS_XBC   83886080l   // xbc   bf16 [2][M,256]     -> 100,663,296
#define WS_MIXED 83886080l   // mixed f32  [M,512] (alias xbc+delta, after scan)
#define WS_DELTA 100663296l  // delta bf16 [2][M,256]     -> 117,440,512
#define WS_BTCT  117440512l  // btct  f32  [2][M,16]      -> 121,634,816

// ---------------- helpers ----------------
__device__ __forceinline__ float b2f(unsigned short u) {
    return __uint_as_float(((unsigned)u) << 16);
}
__device__ __forceinline__ float bload(const bf16* p) {
    return b2f(*(const unsigned short*)p);
}
__device__ __forceinline__ void bstore(bf16* p, float v) {
    *p = __float2bfloat16(v);
}
__device__ __forceinline__ float4 ld4(const float* p) { return *(const float4*)p; }
__device__ __forceinline__ float4 ld4(const bf16* p) {
    ushort4 u = *(const ushort4*)p;
    return make_float4(b2f(u.x), b2f(u.y), b2f(u.z), b2f(u.w));
}
__device__ __forceinline__ void st4(float* p, float4 v) { *(float4*)p = v; }
__device__ __forceinline__ void st4(bf16* p, float4 v) {
    bf16 t[4] = {__float2bfloat16(v.x), __float2bfloat16(v.y),
                 __float2bfloat16(v.z), __float2bfloat16(v.w)};
    *(ushort4*)p = *(ushort4*)t;
}
__device__ __forceinline__ float softplus_f(float x) {
    return fmaxf(x, 0.f) + log1pf(expf(-fabsf(x)));
}
__device__ __forceinline__ float silu_f(float x) {
    return x / (1.f + expf(-x));
}
__device__ __forceinline__ void block_mean_rstd(float v0, float v1, float* red,
                                                float& mean, float& rstd) {
    float s = v0 + v1, q = v0*v0 + v1*v1;
    #pragma unroll
    for (int off = 32; off > 0; off >>= 1) {
        s += __shfl_down(s, off);
        q += __shfl_down(q, off);
    }
    int w = threadIdx.x >> 6, lane = threadIdx.x & 63;
    if (lane == 0) { red[w*2] = s; red[w*2+1] = q; }
    __syncthreads();
    if (threadIdx.x == 0) {
        float ts = 0.f, tq = 0.f;
        #pragma unroll
        for (int i = 0; i < 4; ++i) { ts += red[i*2]; tq += red[i*2+1]; }
        red[8] = ts; red[9] = tq;
    }
    __syncthreads();
    float ts = red[8], tq = red[9];
    mean = ts * (1.f/DDD);
    float var = tq * (1.f/DDD) - mean*mean;
    rstd = rsqrtf(var + 1e-6f);
}

// ---------------- k_si: pos-MLP + LN(x) + add -> si (bf16) ----------------
__global__ __launch_bounds__(256) void k_si(const float* __restrict__ x,
                                            const float* __restrict__ position,
                                            const float* __restrict__ pw1,
                                            const float* __restrict__ pb1,
                                            const float* __restrict__ pw2,
                                            const float* __restrict__ pb2,
                                            const float* __restrict__ lnw,
                                            const float* __restrict__ lnb,
                                            bf16* __restrict__ si) {
    __shared__ float h[128];
    __shared__ float red[10];
    long row = blockIdx.x; int t = threadIdx.x;
    if (t < 128) {
        const float* p = position + row*6;
        const float* w = pw1 + t*6;
        float v = pb1[t];
        #pragma unroll
        for (int j = 0; j < 6; ++j) v = fmaf(p[j], w[j], v);
        h[t] = 0.5f * v * (1.f + erff(v * 0.70710678118654752440f));
    }
    __syncthreads();
    float v0 = x[row*DDD + t], v1 = x[row*DDD + t + 256];
    float mean, rstd;
    block_mean_rstd(v0, v1, red, mean, rstd);
    float p0 = pb2[t], p1 = pb2[t + 256];
    const float* w20 = pw2 + (long)t*128;
    const float* w21 = pw2 + (long)(t + 256)*128;
    for (int k = 0; k < 128; ++k) {
        float hk = h[k];
        p0 = fmaf(hk, w20[k], p0);
        p1 = fmaf(hk, w21[k], p1);
    }
    bstore(si + row*DDD + t,       (v0-mean)*rstd*lnw[t]     + lnb[t]     + p0);
    bstore(si + row*DDD + t + 256, (v1-mean)*rstd*lnw[t+256] + lnb[t+256] + p1);
}

// ---------------- tiled GEMM: C[M,N] = A[M,K] @ B^T (+C if ACCUM) ----------------
// A: bf16 [M,K] lda; B: f32 [N,K] ldb; C: TC [M,N] ldc
template<bool ACCUM, typename TC>
__global__ __launch_bounds__(256)
void gemm_bt(const bf16* __restrict__ A, long lda,
             const float* __restrict__ Bm, long ldb,
             TC* __restrict__ C, long ldc, int Kdim) {
    __shared__ float As[8][132];
    __shared__ float Bs[8][132];
    const int tid = threadIdx.x;
    const int tx = tid & 15;
    const int ty = tid >> 4;
    const long m0 = (long)blockIdx.y * 128;
    const long n0 = (long)blockIdx.x * 128;
    float acc[8][8];
    #pragma unroll
    for (int i = 0; i < 8; ++i)
        #pragma unroll
        for (int j = 0; j < 8; ++j) acc[i][j] = 0.f;

    for (int k0 = 0; k0 < Kdim; k0 += 8) {
        {
            int idx = tid * 4;
            int m = idx >> 3, kk = idx & 7;
            float4 t4 = ld4(A + (m0+m)*lda + k0 + kk);
            As[kk+0][m] = t4.x; As[kk+1][m] = t4.y;
            As[kk+2][m] = t4.z; As[kk+3][m] = t4.w;
        }
        {
            int idx = tid * 4;
            int n = idx >> 3, kk = idx & 7;
            float4 t4 = ld4(Bm + (n0+n)*ldb + k0 + kk);
            Bs[kk+0][n] = t4.x; Bs[kk+1][n] = t4.y;
            Bs[kk+2][n] = t4.z; Bs[kk+3][n] = t4.w;
        }
        __syncthreads();
        #pragma unroll
        for (int kk = 0; kk < 8; ++kk) {
            float a[8], b[8];
            #pragma unroll
            for (int i = 0; i < 8; i += 4)
                *(float4*)&a[i] = *(const float4*)&As[kk][ty*8 + i];
            #pragma unroll
            for (int j = 0; j < 8; j += 4)
                *(float4*)&b[j] = *(const float4*)&Bs[kk][tx*8 + j];
            #pragma unroll
            for (int i = 0; i < 8; ++i)
                #pragma unroll
                for (int j = 0; j < 8; ++j)
                    acc[i][j] = fmaf(a[i], b[j], acc[i][j]);
        }
        __syncthreads();
    }
    #pragma unroll
    for (int i = 0; i < 8; ++i)
        #pragma unroll
        for (int j = 0; j < 8; j += 4) {
            long off = (m0 + ty*8 + i)*ldc + n0 + tx*8 + j;
            float4 v = *(const float4*)&acc[i][j];
            if (ACCUM) {
                float4 old = ld4(C + off);
                v.x += old.x; v.y += old.y; v.z += old.z; v.w += old.w;
            }
            st4(C + off, v);
        }
}

// ---------------- depthwise conv3 + SiLU; xb -> xbc, zb -> u_d[:,256:512] ----------------
__global__ __launch_bounds__(256) void k_conv(const bf16* __restrict__ xz,
                                              const float* __restrict__ cxw,
                                              const float* __restrict__ czw,
                                              bf16* __restrict__ xbc,
                                              bf16* __restrict__ u0,
                                              bf16* __restrict__ u1) {
    int d = blockIdx.y;
    long idx = (long)blockIdx.x*256 + threadIdx.x;
    long row = idx >> 8; int i = idx & 255;
    long l = row & (LL-1);
    const bf16* base = xz + row*1024 + (long)d*512;
    float xv[3], zv[3];
    #pragma unroll
    for (int k = 0; k < 3; ++k) {
        bool ok = (l + k >= 1) && (l + k <= LL);     // 0 <= l+k-1 <= L-1
        xv[k] = ok ? bload(base + (long)(k-1)*1024 + i)       : 0.f;
        zv[k] = ok ? bload(base + (long)(k-1)*1024 + 256 + i) : 0.f;
    }
    const float* wx = cxw + d*(II*3) + i*3;
    const float* wz = czw + d*(II*3) + i*3;
    float ax = 0.f, az = 0.f;
    #pragma unroll
    for (int k = 0; k < 3; ++k) {
        int kk = d ? (2-k) : k;    // reversed taps == conv on flipped sequence
        ax = fmaf(xv[k], wx[kk], ax);
        az = fmaf(zv[k], wz[kk], az);
    }
    bstore(xbc + (long)d*MM*II + row*II + i, silu_f(ax));
    bf16* u = d ? u1 : u0;
    bstore(u + row*512 + 256 + i, silu_f(az));
}

// ---------------- proj -> delta / bt / ct per row ----------------
__global__ __launch_bounds__(256) void k_projdt(const bf16* __restrict__ xbc,
                                                const float* __restrict__ xpw,
                                                const float* __restrict__ dtw,
                                                const float* __restrict__ dtb,
                                                bf16* __restrict__ delta,
                                                float* __restrict__ btct) {
    int d = blockIdx.y;
    long row = blockIdx.x;
    __shared__ float xr[II];
    __shared__ float pr[48];
    int t = threadIdx.x;
    xr[t] = bload(xbc + (long)d*MM*II + row*II + t);
    __syncthreads();
    if (t < 48) {
        const float* w = xpw + (long)d*48*II + t*II;
        float acc = 0.f;
        for (int k = 0; k < II; ++k) acc = fmaf(w[k], xr[k], acc);
        pr[t] = acc;
    }
    __syncthreads();
    {
        const float* w = dtw + (long)d*II*32 + t*32;
        float acc = dtb[d*II + t];
        #pragma unroll
        for (int j = 0; j < 32; ++j) acc = fmaf(w[j], pr[j], acc);
        float sp = softplus_f(acc);
        bstore(delta + (long)d*MM*II + row*II + t, fminf(fmaxf(sp, 1e-4f), 1.0f));
    }
    if (t < 16) btct[(long)d*MM*16 + row*16 + t] = tanhf(pr[32 + t]);
}

// ---------------- literal sequential selective scan ----------------
__global__ __launch_bounds__(256) void k_scan_seq(const bf16* __restrict__ delta,
                                                  const float* __restrict__ btct,
                                                  const bf16* __restrict__ xbc,
                                                  const float* __restrict__ Alog,
                                                  const float* __restrict__ Dp,
                                                  bf16* __restrict__ u0,
                                                  bf16* __restrict__ u1) {
    int z = blockIdx.y;            // d*8 + b
    int d = z >> 3, b = z & 7;
    int il = threadIdx.x >> 3, s = threadIdx.x & 7;
    int i = blockIdx.x*32 + il;
    float a = softplus_f(Alog[(long)d*II*SS + i*SS + s]) + 1e-4f;
    float dpv = Dp[d*II + i];
    const bf16*  del = delta + (long)d*MM*II;
    const bf16*  xb  = xbc   + (long)d*MM*II;
    const float* bc  = btct  + (long)d*MM*16;
    bf16* u = d ? u1 : u0;
    float st = 0.f;
    for (int t = 0; t < LL; ++t) {
        long l = d ? (LL-1-t) : t;          // dir-1 scans the flipped sequence
        long row = (long)b*LL + l;
        float dv  = bload(del + row*II + i);
        float btv = bc[row*16 + s];
        float ctv = bc[row*16 + 8 + s];
        float xv  = bload(xb + row*II + i);
        float dec = fminf(fmaxf(expf(-dv*a), 1e-4f), 1.0f);
        st = fmaf(dec, st, (1.f-dec)*btv*xv);
        float pa = st * ctv;
        pa += __shfl_xor(pa, 1);
        pa += __shfl_xor(pa, 2);
        pa += __shfl_xor(pa, 4);
        if (s == 0) bstore(u + row*512 + i, pa + dpv*xv);
    }
}

// ---------------- final LN -> FLOAT32 output ----------------
__global__ __launch_bounds__(256) void k_ln_out(const float* __restrict__ mixed,
                                                const float* __restrict__ w,
                                                const float* __restrict__ b,
                                                float* __restrict__ out) {
    __shared__ float red[10];
    long row = blockIdx.x; int t = threadIdx.x;
    float v0 = mixed[row*DDD + t], v1 = mixed[row*DDD + t + 256];
    float mean, rstd;
    block_mean_rstd(v0, v1, red, mean, rstd);
    out[row*DDD + t]       = (v0-mean)*rstd*w[t]     + b[t];
    out[row*DDD + t + 256] = (v1-mean)*rstd*w[t+256] + b[t+256];
}

extern "C" void kernel_launch(void* const* d_in, const int* in_sizes, int n_in,
                              void* d_out, int out_size, void* d_ws, size_t ws_size,
                              hipStream_t stream) {
    const float* x        = (const float*)d_in[0];
    const float* position = (const float*)d_in[1];
    const float* ln_in_w  = (const float*)d_in[2];
    const float* ln_in_b  = (const float*)d_in[3];
    const float* pos_w1   = (const float*)d_in[4];
    const float* pos_b1   = (const float*)d_in[5];
    const float* pos_w2   = (const float*)d_in[6];
    const float* pos_b2   = (const float*)d_in[7];
    const float* in_w     = (const float*)d_in[8];   // [2,512,512] as [1024,512]
    const float* cx_w     = (const float*)d_in[9];
    const float* cz_w     = (const float*)d_in[10];
    const float* xp_w     = (const float*)d_in[11];
    const float* dt_w     = (const float*)d_in[12];
    const float* dt_b     = (const float*)d_in[13];
    const float* Alog     = (const float*)d_in[14];
    const float* Dp       = (const float*)d_in[15];
    const float* out_w    = (const float*)d_in[16];  // [2,512,512]
    const float* mix_w    = (const float*)d_in[17];  // [512,1536]
    const float* ln_out_w = (const float*)d_in[18];
    const float* ln_out_b = (const float*)d_in[19];
    float* out = (float*)d_out;                      // reference output dtype = float32

    char* base = (char*)d_ws;
    bf16*  si    = (bf16*)(base + WS_SI);
    bf16*  u0    = (bf16*)(base + WS_U0);
    bf16*  u1    = (bf16*)(base + WS_U1);
    bf16*  xz    = (bf16*)(base + WS_XZ);
    bf16*  fwd   = (bf16*)(base + WS_FWD);    // alias xz (xz dead after conv)
    bf16*  bwd   = (bf16*)(base + WS_BWD);
    bf16*  xbc   = (bf16*)(base + WS_XBC);
    bf16*  delta = (bf16*)(base + WS_DELTA);
    float* btct  = (float*)(base + WS_BTCT);
    float* mixed = (float*)(base + WS_MIXED); // alias xbc+delta (dead after scan)

    // 1. si = LN(x) + posMLP(position)
    k_si<<<MM, 256, 0, stream>>>(x, position, pos_w1, pos_b1, pos_w2, pos_b2,
                                 ln_in_w, ln_in_b, si);
    // 2. in-proj both dirs: xz[M,1024] = si @ in_w^T
    gemm_bt<false, bf16><<<dim3(8, MM/128), 256, 0, stream>>>(si, 512, in_w, 512,
                                                              xz, 1024, 512);
    // 3. depthwise conv + SiLU; xb -> xbc, zb -> u0/u1[:,256:]
    k_conv<<<dim3((MM*II)/256, 2), 256, 0, stream>>>(xz, cx_w, cz_w, xbc, u0, u1);
    // 4. proj -> delta / bt / ct
    k_projdt<<<dim3(MM, 2), 256, 0, stream>>>(xbc, xp_w, dt_w, dt_b, delta, btct);
    // 5. literal sequential scan; y -> u0/u1[:,0:256]
    k_scan_seq<<<dim3(II/32, 16), 256, 0, stream>>>(delta, btct, xbc, Alog, Dp, u0, u1);
    // 6. out-proj: fwd = u0 @ out_w0^T ; bwd = u1 @ out_w1^T   (over dead xz)
    gemm_bt<false, bf16><<<dim3(4, MM/128), 256, 0, stream>>>(u0, 512, out_w, 512,
                                                              fwd, 512, 512);
    gemm_bt<false, bf16><<<dim3(4, MM/128), 256, 0, stream>>>(u1, 512, out_w + 512l*512, 512,
                                                              bwd, 512, 512);
    // 7. mixed = fwd@Wm0^T + bwd@Wm1^T + si@Wm2^T   (over dead xbc+delta)
    gemm_bt<false, float><<<dim3(4, MM/128), 256, 0, stream>>>(fwd, 512, mix_w, 1536,
                                                               mixed, 512, 512);
    gemm_bt<true,  float><<<dim3(4, MM/128), 256, 0, stream>>>(bwd, 512, mix_w + 512, 1536,
                                                               mixed, 512, 512);
    gemm_bt<true,  float><<<dim3(4, MM/128), 256, 0, stream>>>(si, 512, mix_w + 1024, 1536,
                                                               mixed, 512, 512);
    // 8. out = LN(mixed) -> f32
    k_ln_out<<<MM, 256, 0, stream>>>(mixed, ln_out_w, ln_out_b, out);
}

// Round 9
// 1214.671 us; speedup vs baseline: 2.0811x; 2.0811x over previous
//
#include <hip/hip_runtime.h>
#include <hip/hip_bf16.h>

typedef __hip_bfloat16 bf16;
typedef __attribute__((ext_vector_type(8))) short short8;
typedef __attribute__((ext_vector_type(4))) float floatx4;

#define BBB 8
#define LL 2048
#define DDD 512
#define II 256
#define SS 8
#define MM (BBB*LL)      // 16384 rows
#define CHUNK 32
#define NCH (LL/CHUNK)   // 64

// ---- workspace (bytes); proven ws_size >= 131,072,000 (R2/R4 ran with this) ----
#define WS_SI    0l          // si    bf16 [M,512]          -> 16,777,216
#define WS_U0    16777216l   // u0    bf16 [M,512] (y0|zb0) -> 33,554,432
#define WS_U1    33554432l   // u1    bf16 [M,512] (y1|zb1) -> 50,331,648
#define WS_XZ    50331648l   // xz    bf16 [M,1024]         -> 83,886,080
//   scratch region reuse (all lifetimes disjoint):
#define WS_P     50331648l   // P f32 [16][64][2048] -> +8,388,608   (after conv)
#define WS_Q     58720256l   // Q f32                 -> +8,388,608
#define WS_SINB  67108864l   // sinb f32              -> +8,388,608  (ends 75,497,472)
#define WS_FWD   50331648l   // fwd bf16 [M,512] (after scan3)
#define WS_BWD   67108864l   // bwd bf16 [M,512]
#define WS_XBC   83886080l   // xbc   bf16 [2][M,256]       -> 100,663,296
#define WS_MIXED 83886080l   // mixed f32 [M,512] (alias xbc+delta, after scan)
#define WS_DELTA 100663296l  // delta bf16 [2][M,256]       -> 117,440,512
#define WS_BTCT  117440512l  // btct  f32  [2][M,16]        -> 121,634,816
#define WS_INWB  121634816l  // in_w  bf16 [1024,512]       -> 122,683,392
#define WS_OUTWB 122683392l  // out_w bf16 [2,512,512]      -> 123,731,968
#define WS_MIXWB 123731968l  // mix_w bf16 [512,1536]       -> 125,304,832

// ---------------- helpers ----------------
__device__ __forceinline__ float b2f(unsigned short u) {
    return __uint_as_float(((unsigned)u) << 16);
}
__device__ __forceinline__ float bload(const bf16* p) {
    return b2f(*(const unsigned short*)p);
}
__device__ __forceinline__ void bstore(bf16* p, float v) {
    *p = __float2bfloat16(v);
}
__device__ __forceinline__ float softplus_f(float x) {
    return fmaxf(x, 0.f) + log1pf(expf(-fabsf(x)));
}
__device__ __forceinline__ float silu_f(float x) {
    return x / (1.f + expf(-x));
}
__device__ __forceinline__ void block_mean_rstd(float v0, float v1, float* red,
                                                float& mean, float& rstd) {
    float s = v0 + v1, q = v0*v0 + v1*v1;
    #pragma unroll
    for (int off = 32; off > 0; off >>= 1) {
        s += __shfl_down(s, off);
        q += __shfl_down(q, off);
    }
    int w = threadIdx.x >> 6, lane = threadIdx.x & 63;
    if (lane == 0) { red[w*2] = s; red[w*2+1] = q; }
    __syncthreads();
    if (threadIdx.x == 0) {
        float ts = 0.f, tq = 0.f;
        #pragma unroll
        for (int i = 0; i < 4; ++i) { ts += red[i*2]; tq += red[i*2+1]; }
        red[8] = ts; red[9] = tq;
    }
    __syncthreads();
    float ts = red[8], tq = red[9];
    mean = ts * (1.f/DDD);
    float var = tq * (1.f/DDD) - mean*mean;
    rstd = rsqrtf(var + 1e-6f);
}

// ---------------- f32 -> bf16 weight conversion ----------------
__global__ __launch_bounds__(256) void k_f2b(const float* __restrict__ src,
                                             bf16* __restrict__ dst, int n) {
    int i = (blockIdx.x*256 + threadIdx.x) * 4;
    if (i >= n) return;
    float4 v = *(const float4*)(src + i);
    bf16 t[4] = {__float2bfloat16(v.x), __float2bfloat16(v.y),
                 __float2bfloat16(v.z), __float2bfloat16(v.w)};
    *(ushort4*)(dst + i) = *(ushort4*)t;
}

// ---------------- k_si: pos-MLP + LN(x) + add -> si (bf16) ----------------
__global__ __launch_bounds__(256) void k_si(const float* __restrict__ x,
                                            const float* __restrict__ position,
                                            const float* __restrict__ pw1,
                                            const float* __restrict__ pb1,
                                            const float* __restrict__ pw2,
                                            const float* __restrict__ pb2,
                                            const float* __restrict__ lnw,
                                            const float* __restrict__ lnb,
                                            bf16* __restrict__ si) {
    __shared__ float h[128];
    __shared__ float red[10];
    long row = blockIdx.x; int t = threadIdx.x;
    if (t < 128) {
        const float* p = position + row*6;
        const float* w = pw1 + t*6;
        float v = pb1[t];
        #pragma unroll
        for (int j = 0; j < 6; ++j) v = fmaf(p[j], w[j], v);
        h[t] = 0.5f * v * (1.f + erff(v * 0.70710678118654752440f));
    }
    __syncthreads();
    float v0 = x[row*DDD + t], v1 = x[row*DDD + t + 256];
    float mean, rstd;
    block_mean_rstd(v0, v1, red, mean, rstd);
    float p0 = pb2[t], p1 = pb2[t + 256];
    const float* w20 = pw2 + (long)t*128;
    const float* w21 = pw2 + (long)(t + 256)*128;
    for (int k = 0; k < 128; ++k) {
        float hk = h[k];
        p0 = fmaf(hk, w20[k], p0);
        p1 = fmaf(hk, w21[k], p1);
    }
    bstore(si + row*DDD + t,       (v0-mean)*rstd*lnw[t]     + lnb[t]     + p0);
    bstore(si + row*DDD + t + 256, (v1-mean)*rstd*lnw[t+256] + lnb[t+256] + p1);
}

// ---------------- MFMA GEMM: C[M,N] = A[M,K] @ B^T (+C if ACCUM) ----------------
// A: bf16 [M,K]; B: bf16 [N,K]; acc f32. Tile 128x128, BK=32, 4 waves x (4x4) 16x16x32.
// Verified layouts (learn_hip m89): A[m=lane&15][k=quad*8+j]; B[n=lane&15][k=quad*8+j];
// C/D: col=lane&15, row=quad*4+reg.
template<bool ACCUM, typename TC>
__global__ __launch_bounds__(256)
void gemm_mfma(const bf16* __restrict__ A, long lda,
               const bf16* __restrict__ B, long ldb,
               TC* __restrict__ C, long ldc, int Kdim) {
    __shared__ short As[128][40];   // +8 pad breaks bank conflicts
    __shared__ short Bs[128][40];
    const int tid = threadIdx.x;
    const int lane = tid & 63;
    const int wave = tid >> 6;
    const int wm = wave >> 1, wn = wave & 1;
    const long m0 = (long)blockIdx.y * 128;
    const long n0 = (long)blockIdx.x * 128;
    const int lr = lane & 15;
    const int lq = lane >> 4;
    floatx4 acc[4][4];
    #pragma unroll
    for (int i = 0; i < 4; ++i)
        #pragma unroll
        for (int j = 0; j < 4; ++j)
            acc[i][j] = (floatx4){0.f, 0.f, 0.f, 0.f};

    for (int k0 = 0; k0 < Kdim; k0 += 32) {
        #pragma unroll
        for (int q = 0; q < 2; ++q) {
            int e = (tid + q*256) * 8;        // 4096 bf16 per tile
            int r = e >> 5, c = e & 31;
            *(short8*)&As[r][c] = *(const short8*)(A + (m0+r)*lda + k0 + c);
            *(short8*)&Bs[r][c] = *(const short8*)(B + (n0+r)*ldb + k0 + c);
        }
        __syncthreads();
        short8 af[4], bfr[4];
        #pragma unroll
        for (int mi = 0; mi < 4; ++mi)
            af[mi] = *(const short8*)&As[wm*64 + mi*16 + lr][lq*8];
        #pragma unroll
        for (int ni = 0; ni < 4; ++ni)
            bfr[ni] = *(const short8*)&Bs[wn*64 + ni*16 + lr][lq*8];
        #pragma unroll
        for (int mi = 0; mi < 4; ++mi)
            #pragma unroll
            for (int ni = 0; ni < 4; ++ni)
                acc[mi][ni] = __builtin_amdgcn_mfma_f32_16x16x32_bf16(
                    af[mi], bfr[ni], acc[mi][ni], 0, 0, 0);
        __syncthreads();
    }
    #pragma unroll
    for (int mi = 0; mi < 4; ++mi)
        #pragma unroll
        for (int ni = 0; ni < 4; ++ni)
            #pragma unroll
            for (int r = 0; r < 4; ++r) {
                long row = m0 + wm*64 + mi*16 + lq*4 + r;
                long col = n0 + wn*64 + ni*16 + lr;
                float v = acc[mi][ni][r];
                if (ACCUM) v += ((const float*)C)[row*ldc + col];
                if constexpr (sizeof(TC) == 2) bstore((bf16*)C + row*ldc + col, v);
                else ((float*)C)[row*ldc + col] = v;
            }
}

// ---------------- depthwise conv3 + SiLU; xb -> xbc, zb -> u_d[:,256:512] ----------------
__global__ __launch_bounds__(256) void k_conv(const bf16* __restrict__ xz,
                                              const float* __restrict__ cxw,
                                              const float* __restrict__ czw,
                                              bf16* __restrict__ xbc,
                                              bf16* __restrict__ u0,
                                              bf16* __restrict__ u1) {
    int d = blockIdx.y;
    long idx = (long)blockIdx.x*256 + threadIdx.x;
    long row = idx >> 8; int i = idx & 255;
    long l = row & (LL-1);
    const bf16* base = xz + row*1024 + (long)d*512;
    float xv[3], zv[3];
    #pragma unroll
    for (int k = 0; k < 3; ++k) {
        bool ok = (l + k >= 1) && (l + k <= LL);
        xv[k] = ok ? bload(base + (long)(k-1)*1024 + i)       : 0.f;
        zv[k] = ok ? bload(base + (long)(k-1)*1024 + 256 + i) : 0.f;
    }
    const float* wx = cxw + d*(II*3) + i*3;
    const float* wz = czw + d*(II*3) + i*3;
    float ax = 0.f, az = 0.f;
    #pragma unroll
    for (int k = 0; k < 3; ++k) {
        int kk = d ? (2-k) : k;
        ax = fmaf(xv[k], wx[kk], ax);
        az = fmaf(zv[k], wz[kk], az);
    }
    bstore(xbc + (long)d*MM*II + row*II + i, silu_f(ax));
    bf16* u = d ? u1 : u0;
    bstore(u + row*512 + 256 + i, silu_f(az));
}

// ---------------- proj -> delta / bt / ct per row ----------------
__global__ __launch_bounds__(256) void k_projdt(const bf16* __restrict__ xbc,
                                                const float* __restrict__ xpw,
                                                const float* __restrict__ dtw,
                                                const float* __restrict__ dtb,
                                                bf16* __restrict__ delta,
                                                float* __restrict__ btct) {
    int d = blockIdx.y;
    long row = blockIdx.x;
    __shared__ float xr[II];
    __shared__ float pr[48];
    int t = threadIdx.x;
    xr[t] = bload(xbc + (long)d*MM*II + row*II + t);
    __syncthreads();
    if (t < 48) {
        const float* w = xpw + (long)d*48*II + t*II;
        float acc = 0.f;
        for (int k = 0; k < II; ++k) acc = fmaf(w[k], xr[k], acc);
        pr[t] = acc;
    }
    __syncthreads();
    {
        const float* w = dtw + (long)d*II*32 + t*32;
        float acc = dtb[d*II + t];
        #pragma unroll
        for (int j = 0; j < 32; ++j) acc = fmaf(w[j], pr[j], acc);
        float sp = softplus_f(acc);
        bstore(delta + (long)d*MM*II + row*II + t, fminf(fmaxf(sp, 1e-4f), 1.0f));
    }
    if (t < 16) btct[(long)d*MM*16 + row*16 + t] = tanhf(pr[32 + t]);
}

// ---------------- scan pass 1: per-chunk affine transfer (P,Q) f32 ----------------
__global__ __launch_bounds__(256) void k_scan1(const bf16* __restrict__ delta,
                                               const float* __restrict__ btct,
                                               const bf16* __restrict__ xbc,
                                               const float* __restrict__ Alog,
                                               float* __restrict__ P,
                                               float* __restrict__ Q) {
    int z = blockIdx.z;            // d*8 + b
    int d = z >> 3, b = z & 7;
    int c = blockIdx.y;
    int il = threadIdx.x >> 3, s = threadIdx.x & 7;
    int i = blockIdx.x*32 + il;
    float a = softplus_f(Alog[(long)d*II*SS + i*SS + s]) + 1e-4f;
    const bf16*  del = delta + (long)d*MM*II;
    const bf16*  xb  = xbc   + (long)d*MM*II;
    const float* bc  = btct  + (long)d*MM*16;
    float Pv = 1.f, Qv = 0.f;
    for (int tt = 0; tt < CHUNK; ++tt) {
        int t = c*CHUNK + tt;
        long l = d ? (LL-1-t) : t;
        long row = (long)b*LL + l;
        float dv  = bload(del + row*II + i);
        float btv = bc[row*16 + s];
        float xv  = bload(xb + row*II + i);
        float dec = fminf(fmaxf(expf(-dv*a), 1e-4f), 1.0f);
        Pv *= dec;
        Qv = fmaf(dec, Qv, (1.f-dec)*btv*xv);
    }
    long o = ((long)z*NCH + c)*2048 + (long)i*8 + s;
    P[o] = Pv; Q[o] = Qv;
}

// ---------------- scan pass 2: serial chunk combine ----------------
__global__ __launch_bounds__(256) void k_scan2(const float* __restrict__ P,
                                               const float* __restrict__ Q,
                                               float* __restrict__ sinb) {
    int d = blockIdx.y;
    long idx = (long)blockIdx.x*256 + threadIdx.x;  // 16384 per dir
    int b = (int)(idx >> 11); int rem = (int)(idx & 2047);
    long base = ((long)(d*8 + b)*NCH)*2048 + rem;
    float st = 0.f;
    for (int c = 0; c < NCH; ++c) {
        long o = base + (long)c*2048;
        sinb[o] = st;
        st = fmaf(P[o], st, Q[o]);
    }
}

// ---------------- scan pass 3: replay with state, emit y ----------------
__global__ __launch_bounds__(256) void k_scan3(const bf16* __restrict__ delta,
                                               const float* __restrict__ btct,
                                               const bf16* __restrict__ xbc,
                                               const float* __restrict__ Alog,
                                               const float* __restrict__ Dp,
                                               const float* __restrict__ sinb,
                                               bf16* __restrict__ u0,
                                               bf16* __restrict__ u1) {
    int z = blockIdx.z;
    int d = z >> 3, b = z & 7;
    int c = blockIdx.y;
    int il = threadIdx.x >> 3, s = threadIdx.x & 7;
    int i = blockIdx.x*32 + il;
    float a = softplus_f(Alog[(long)d*II*SS + i*SS + s]) + 1e-4f;
    float dpv = Dp[d*II + i];
    const bf16*  del = delta + (long)d*MM*II;
    const bf16*  xb  = xbc   + (long)d*MM*II;
    const float* bc  = btct  + (long)d*MM*16;
    bf16* u = d ? u1 : u0;
    float st = sinb[((long)z*NCH + c)*2048 + (long)i*8 + s];
    for (int tt = 0; tt < CHUNK; ++tt) {
        int t = c*CHUNK + tt;
        long l = d ? (LL-1-t) : t;
        long row = (long)b*LL + l;
        float dv  = bload(del + row*II + i);
        float btv = bc[row*16 + s];
        float ctv = bc[row*16 + 8 + s];
        float xv  = bload(xb + row*II + i);
        float dec = fminf(fmaxf(expf(-dv*a), 1e-4f), 1.0f);
        st = fmaf(dec, st, (1.f-dec)*btv*xv);
        float pa = st * ctv;
        pa += __shfl_xor(pa, 1);
        pa += __shfl_xor(pa, 2);
        pa += __shfl_xor(pa, 4);
        if (s == 0) bstore(u + row*512 + i, pa + dpv*xv);
    }
}

// ---------------- final LN -> f32 output ----------------
__global__ __launch_bounds__(256) void k_ln_out(const float* __restrict__ mixed,
                                                const float* __restrict__ w,
                                                const float* __restrict__ b,
                                                float* __restrict__ out) {
    __shared__ float red[10];
    long row = blockIdx.x; int t = threadIdx.x;
    float v0 = mixed[row*DDD + t], v1 = mixed[row*DDD + t + 256];
    float mean, rstd;
    block_mean_rstd(v0, v1, red, mean, rstd);
    out[row*DDD + t]       = (v0-mean)*rstd*w[t]     + b[t];
    out[row*DDD + t + 256] = (v1-mean)*rstd*w[t+256] + b[t+256];
}

extern "C" void kernel_launch(void* const* d_in, const int* in_sizes, int n_in,
                              void* d_out, int out_size, void* d_ws, size_t ws_size,
                              hipStream_t stream) {
    const float* x        = (const float*)d_in[0];
    const float* position = (const float*)d_in[1];
    const float* ln_in_w  = (const float*)d_in[2];
    const float* ln_in_b  = (const float*)d_in[3];
    const float* pos_w1   = (const float*)d_in[4];
    const float* pos_b1   = (const float*)d_in[5];
    const float* pos_w2   = (const float*)d_in[6];
    const float* pos_b2   = (const float*)d_in[7];
    const float* in_w     = (const float*)d_in[8];
    const float* cx_w     = (const float*)d_in[9];
    const float* cz_w     = (const float*)d_in[10];
    const float* xp_w     = (const float*)d_in[11];
    const float* dt_w     = (const float*)d_in[12];
    const float* dt_b     = (const float*)d_in[13];
    const float* Alog     = (const float*)d_in[14];
    const float* Dp       = (const float*)d_in[15];
    const float* out_w    = (const float*)d_in[16];
    const float* mix_w    = (const float*)d_in[17];
    const float* ln_out_w = (const float*)d_in[18];
    const float* ln_out_b = (const float*)d_in[19];
    float* out = (float*)d_out;

    char* base = (char*)d_ws;
    bf16*  si    = (bf16*)(base + WS_SI);
    bf16*  u0    = (bf16*)(base + WS_U0);
    bf16*  u1    = (bf16*)(base + WS_U1);
    bf16*  xz    = (bf16*)(base + WS_XZ);
    float* Pb    = (float*)(base + WS_P);
    float* Qb    = (float*)(base + WS_Q);
    float* sinb  = (float*)(base + WS_SINB);
    bf16*  fwd   = (bf16*)(base + WS_FWD);
    bf16*  bwd   = (bf16*)(base + WS_BWD);
    bf16*  xbc   = (bf16*)(base + WS_XBC);
    bf16*  delta = (bf16*)(base + WS_DELTA);
    float* btct  = (float*)(base + WS_BTCT);
    float* mixed = (float*)(base + WS_MIXED);
    bf16*  in_wb  = (bf16*)(base + WS_INWB);
    bf16*  out_wb = (bf16*)(base + WS_OUTWB);
    bf16*  mix_wb = (bf16*)(base + WS_MIXWB);

    // 0. weight conversion f32 -> bf16
    k_f2b<<<(524288/4+255)/256, 256, 0, stream>>>(in_w,  in_wb,  524288);
    k_f2b<<<(524288/4+255)/256, 256, 0, stream>>>(out_w, out_wb, 524288);
    k_f2b<<<(786432/4+255)/256, 256, 0, stream>>>(mix_w, mix_wb, 786432);

    // 1. si = LN(x) + posMLP(position)
    k_si<<<MM, 256, 0, stream>>>(x, position, pos_w1, pos_b1, pos_w2, pos_b2,
                                 ln_in_w, ln_in_b, si);
    // 2. in-proj: xz[M,1024] = si @ in_w^T   (MFMA)
    gemm_mfma<false, bf16><<<dim3(8, MM/128), 256, 0, stream>>>(si, 512, in_wb, 512,
                                                                xz, 1024, 512);
    // 3. conv + SiLU
    k_conv<<<dim3((MM*II)/256, 2), 256, 0, stream>>>(xz, cx_w, cz_w, xbc, u0, u1);
    // 4. proj -> delta / bt / ct
    k_projdt<<<dim3(MM, 2), 256, 0, stream>>>(xbc, xp_w, dt_w, dt_b, delta, btct);
    // 5. chunked scan (P/Q/sinb overwrite dead xz region)
    k_scan1<<<dim3(II/32, NCH, 16), 256, 0, stream>>>(delta, btct, xbc, Alog, Pb, Qb);
    k_scan2<<<dim3(64, 2), 256, 0, stream>>>(Pb, Qb, sinb);
    k_scan3<<<dim3(II/32, NCH, 16), 256, 0, stream>>>(delta, btct, xbc, Alog, Dp,
                                                      sinb, u0, u1);
    // 6. out-proj (MFMA); fwd/bwd overwrite dead P/sinb
    gemm_mfma<false, bf16><<<dim3(4, MM/128), 256, 0, stream>>>(u0, 512, out_wb, 512,
                                                                fwd, 512, 512);
    gemm_mfma<false, bf16><<<dim3(4, MM/128), 256, 0, stream>>>(u1, 512, out_wb + 512l*512,
                                                                512, bwd, 512, 512);
    // 7. mixed = fwd@Wm0^T + bwd@Wm1^T + si@Wm2^T  (MFMA, f32 accum in global)
    gemm_mfma<false, float><<<dim3(4, MM/128), 256, 0, stream>>>(fwd, 512, mix_wb, 1536,
                                                                 mixed, 512, 512);
    gemm_mfma<true,  float><<<dim3(4, MM/128), 256, 0, stream>>>(bwd, 512, mix_wb + 512,
                                                                 1536, mixed, 512, 512);
    gemm_mfma<true,  float><<<dim3(4, MM/128), 256, 0, stream>>>(si, 512, mix_wb + 1024,
                                                                 1536, mixed, 512, 512);
    // 8. out = LN(mixed) -> f32
    k_ln_out<<<MM, 256, 0, stream>>>(mixed, ln_out_w, ln_out_b, out);
}

// Round 10
// 744.575 us; speedup vs baseline: 3.3950x; 1.6314x over previous
//
#include <hip/hip_runtime.h>
#include <hip/hip_bf16.h>

typedef __hip_bfloat16 bf16;
typedef __attribute__((ext_vector_type(8))) short short8;
typedef __attribute__((ext_vector_type(4))) float floatx4;

#define BBB 8
#define LL 2048
#define DDD 512
#define II 256
#define SS 8
#define MM (BBB*LL)      // 16384 rows
#define CHUNK 32
#define NCH (LL/CHUNK)   // 64

// ---- workspace (bytes); proven ws_size >= 131,072,000 ----
#define WS_SI    0l          // si bf16 [M,512]            -> 16,777,216
#define WS_U0    16777216l   // u0 bf16 [M,512] (y0|zb0)   -> 33,554,432
#define WS_U1    33554432l   // u1 bf16 [M,512] (y1|zb1)   -> 50,331,648
#define WS_XZ    50331648l   // xz bf16 [M,1024]           -> 83,886,080
//   XZ region reuse (disjoint lifetimes):
#define WS_POS   50331648l   // posout bf16 [M,512] (early)      -> +16,777,216
#define WS_H     67108864l   // H bf16 [M,128] (early)           -> +4,194,304
#define WS_P     50331648l   // P f32 [16][64][2048] (after conv)-> +8,388,608
#define WS_Q     58720256l   // Q f32                            -> +8,388,608
#define WS_SINB  67108864l   // sinb f32                         -> +8,388,608
#define WS_XBC   83886080l   // xbc bf16 [2][M,256]        -> 100,663,296
#define WS_MIXED 83886080l   // mixed f32 [M,512] (alias xbc+delta, after scan)
#define WS_DELTA 100663296l  // delta bf16 [2][M,256]      -> 117,440,512
#define WS_BTCT  117440512l  // btct f32 [2][M,16]         -> 121,634,816
#define WS_INWB  121634816l  // in_w  bf16 [1024,512]      -> 122,683,392
#define WS_MIXWB 122683392l  // mix_w bf16 [512,1536]      -> 124,256,256
#define WS_PW2B  124256256l  // pos_w2 bf16 [512,128]      -> 124,387,328
#define WS_OWT   124387328l  // out_w^T bf16 [2][512,512]  -> 125,435,904
#define WS_WP    125435904l  // W' bf16 [2][512,512]       -> 126,484,480

// ---------------- helpers ----------------
__device__ __forceinline__ float b2f(unsigned short u) {
    return __uint_as_float(((unsigned)u) << 16);
}
__device__ __forceinline__ float bload(const bf16* p) {
    return b2f(*(const unsigned short*)p);
}
__device__ __forceinline__ void bstore(bf16* p, float v) {
    *p = __float2bfloat16(v);
}
__device__ __forceinline__ float softplus_f(float x) {
    return fmaxf(x, 0.f) + log1pf(expf(-fabsf(x)));
}
__device__ __forceinline__ float silu_f(float x) {
    return x / (1.f + expf(-x));
}
__device__ __forceinline__ void block_mean_rstd(float v0, float v1, float* red,
                                                float& mean, float& rstd) {
    float s = v0 + v1, q = v0*v0 + v1*v1;
    #pragma unroll
    for (int off = 32; off > 0; off >>= 1) {
        s += __shfl_down(s, off);
        q += __shfl_down(q, off);
    }
    int w = threadIdx.x >> 6, lane = threadIdx.x & 63;
    if (lane == 0) { red[w*2] = s; red[w*2+1] = q; }
    __syncthreads();
    if (threadIdx.x == 0) {
        float ts = 0.f, tq = 0.f;
        #pragma unroll
        for (int i = 0; i < 4; ++i) { ts += red[i*2]; tq += red[i*2+1]; }
        red[8] = ts; red[9] = tq;
    }
    __syncthreads();
    float ts = red[8], tq = red[9];
    mean = ts * (1.f/DDD);
    float var = tq * (1.f/DDD) - mean*mean;
    rstd = rsqrtf(var + 1e-6f);
}

// ---------------- f32 -> bf16 conversion ----------------
__global__ __launch_bounds__(256) void k_f2b(const float* __restrict__ src,
                                             bf16* __restrict__ dst, int n) {
    int i = (blockIdx.x*256 + threadIdx.x) * 4;
    if (i >= n) return;
    float4 v = *(const float4*)(src + i);
    bf16 t[4] = {__float2bfloat16(v.x), __float2bfloat16(v.y),
                 __float2bfloat16(v.z), __float2bfloat16(v.w)};
    *(ushort4*)(dst + i) = *(ushort4*)t;
}

// ---------------- out_w transpose+convert: owT[d][k][c] = out_w[d][c][k] ----------------
__global__ __launch_bounds__(256) void k_tow(const float* __restrict__ ow,
                                             bf16* __restrict__ owT) {
    long idx = (long)blockIdx.x*256 + threadIdx.x;   // 2*512*512
    long d = idx >> 18; long rem = idx & 262143;
    long k = rem >> 9, c = rem & 511;
    bstore(owT + idx, ow[d*262144 + c*512 + k]);
}

// ---------------- H = gelu(position @ pw1^T + pb1) -> bf16 [M,128] ----------------
__global__ __launch_bounds__(256) void k_h(const float* __restrict__ position,
                                           const float* __restrict__ pw1,
                                           const float* __restrict__ pb1,
                                           bf16* __restrict__ H) {
    long idx = (long)blockIdx.x*256 + threadIdx.x;
    long row = idx >> 7; int ph = idx & 127;
    const float* p = position + row*6;
    const float* w = pw1 + ph*6;
    float v = pb1[ph];
    #pragma unroll
    for (int j = 0; j < 6; ++j) v = fmaf(p[j], w[j], v);
    v = 0.5f * v * (1.f + erff(v * 0.70710678118654752440f));
    bstore(H + idx, v);
}

// ---------------- si = LN(x)*w+b + posout + pb2 -> bf16 ----------------
__global__ __launch_bounds__(256) void k_ln_add(const float* __restrict__ x,
                                                const bf16* __restrict__ posout,
                                                const float* __restrict__ lnw,
                                                const float* __restrict__ lnb,
                                                const float* __restrict__ pb2,
                                                bf16* __restrict__ si) {
    __shared__ float red[10];
    long row = blockIdx.x; int t = threadIdx.x;
    float v0 = x[row*DDD + t], v1 = x[row*DDD + t + 256];
    float mean, rstd;
    block_mean_rstd(v0, v1, red, mean, rstd);
    float p0 = bload(posout + row*DDD + t)       + pb2[t];
    float p1 = bload(posout + row*DDD + t + 256) + pb2[t + 256];
    bstore(si + row*DDD + t,       (v0-mean)*rstd*lnw[t]     + lnb[t]     + p0);
    bstore(si + row*DDD + t + 256, (v1-mean)*rstd*lnw[t+256] + lnb[t+256] + p1);
}

// ---------------- MFMA GEMM: C[M,N] = A[M,K] @ B^T (layouts verified m89) ----------------
template<bool ACCUM, typename TC>
__global__ __launch_bounds__(256)
void gemm_mfma(const bf16* __restrict__ A, long lda,
               const bf16* __restrict__ B, long ldb,
               TC* __restrict__ C, long ldc, int Kdim) {
    __shared__ short As[128][40];
    __shared__ short Bs[128][40];
    const int tid = threadIdx.x;
    const int lane = tid & 63;
    const int wave = tid >> 6;
    const int wm = wave >> 1, wn = wave & 1;
    const long m0 = (long)blockIdx.y * 128;
    const long n0 = (long)blockIdx.x * 128;
    const int lr = lane & 15;
    const int lq = lane >> 4;
    floatx4 acc[4][4];
    #pragma unroll
    for (int i = 0; i < 4; ++i)
        #pragma unroll
        for (int j = 0; j < 4; ++j)
            acc[i][j] = (floatx4){0.f, 0.f, 0.f, 0.f};

    for (int k0 = 0; k0 < Kdim; k0 += 32) {
        #pragma unroll
        for (int q = 0; q < 2; ++q) {
            int e = (tid + q*256) * 8;
            int r = e >> 5, c = e & 31;
            *(short8*)&As[r][c] = *(const short8*)(A + (m0+r)*lda + k0 + c);
            *(short8*)&Bs[r][c] = *(const short8*)(B + (n0+r)*ldb + k0 + c);
        }
        __syncthreads();
        short8 af[4], bfr[4];
        #pragma unroll
        for (int mi = 0; mi < 4; ++mi)
            af[mi] = *(const short8*)&As[wm*64 + mi*16 + lr][lq*8];
        #pragma unroll
        for (int ni = 0; ni < 4; ++ni)
            bfr[ni] = *(const short8*)&Bs[wn*64 + ni*16 + lr][lq*8];
        #pragma unroll
        for (int mi = 0; mi < 4; ++mi)
            #pragma unroll
            for (int ni = 0; ni < 4; ++ni)
                acc[mi][ni] = __builtin_amdgcn_mfma_f32_16x16x32_bf16(
                    af[mi], bfr[ni], acc[mi][ni], 0, 0, 0);
        __syncthreads();
    }
    #pragma unroll
    for (int mi = 0; mi < 4; ++mi)
        #pragma unroll
        for (int ni = 0; ni < 4; ++ni)
            #pragma unroll
            for (int r = 0; r < 4; ++r) {
                long row = m0 + wm*64 + mi*16 + lq*4 + r;
                long col = n0 + wn*64 + ni*16 + lr;
                float v = acc[mi][ni][r];
                if (ACCUM) v += ((const float*)C)[row*ldc + col];
                if constexpr (sizeof(TC) == 2) bstore((bf16*)C + row*ldc + col, v);
                else ((float*)C)[row*ldc + col] = v;
            }
}

// ---------------- segmented MFMA GEMM: mixed = [A0|A1|A2] @ [B0|B1|B2]^T ----------------
// A0/A1/A2: bf16 [M,512]; B0/B1: bf16 [512,512] ldb 512; B2: bf16 [512,·] ldb2. K=1536.
__global__ __launch_bounds__(256)
void gemm_mix3(const bf16* __restrict__ A0, const bf16* __restrict__ A1,
               const bf16* __restrict__ A2,
               const bf16* __restrict__ B0, const bf16* __restrict__ B1,
               const bf16* __restrict__ B2, long ldb2,
               float* __restrict__ C) {
    __shared__ short As[128][40];
    __shared__ short Bs[128][40];
    const int tid = threadIdx.x;
    const int lane = tid & 63;
    const int wave = tid >> 6;
    const int wm = wave >> 1, wn = wave & 1;
    const long m0 = (long)blockIdx.y * 128;
    const long n0 = (long)blockIdx.x * 128;
    const int lr = lane & 15;
    const int lq = lane >> 4;
    floatx4 acc[4][4];
    #pragma unroll
    for (int i = 0; i < 4; ++i)
        #pragma unroll
        for (int j = 0; j < 4; ++j)
            acc[i][j] = (floatx4){0.f, 0.f, 0.f, 0.f};

    for (int k0 = 0; k0 < 1536; k0 += 32) {
        const bf16* Ap = (k0 < 512) ? A0 : (k0 < 1024 ? A1 : A2);
        const bf16* Bp = (k0 < 512) ? B0 : (k0 < 1024 ? B1 : B2);
        long ldbv = (k0 < 1024) ? 512 : ldb2;
        int kc = k0 & 511;
        #pragma unroll
        for (int q = 0; q < 2; ++q) {
            int e = (tid + q*256) * 8;
            int r = e >> 5, c = e & 31;
            *(short8*)&As[r][c] = *(const short8*)(Ap + (m0+r)*512 + kc + c);
            *(short8*)&Bs[r][c] = *(const short8*)(Bp + (n0+r)*ldbv + kc + c);
        }
        __syncthreads();
        short8 af[4], bfr[4];
        #pragma unroll
        for (int mi = 0; mi < 4; ++mi)
            af[mi] = *(const short8*)&As[wm*64 + mi*16 + lr][lq*8];
        #pragma unroll
        for (int ni = 0; ni < 4; ++ni)
            bfr[ni] = *(const short8*)&Bs[wn*64 + ni*16 + lr][lq*8];
        #pragma unroll
        for (int mi = 0; mi < 4; ++mi)
            #pragma unroll
            for (int ni = 0; ni < 4; ++ni)
                acc[mi][ni] = __builtin_amdgcn_mfma_f32_16x16x32_bf16(
                    af[mi], bfr[ni], acc[mi][ni], 0, 0, 0);
        __syncthreads();
    }
    #pragma unroll
    for (int mi = 0; mi < 4; ++mi)
        #pragma unroll
        for (int ni = 0; ni < 4; ++ni)
            #pragma unroll
            for (int r = 0; r < 4; ++r) {
                long row = m0 + wm*64 + mi*16 + lq*4 + r;
                long col = n0 + wn*64 + ni*16 + lr;
                C[row*512 + col] = acc[mi][ni][r];
            }
}

// ---------------- depthwise conv3 + SiLU ----------------
__global__ __launch_bounds__(256) void k_conv(const bf16* __restrict__ xz,
                                              const float* __restrict__ cxw,
                                              const float* __restrict__ czw,
                                              bf16* __restrict__ xbc,
                                              bf16* __restrict__ u0,
                                              bf16* __restrict__ u1) {
    int d = blockIdx.y;
    long idx = (long)blockIdx.x*256 + threadIdx.x;
    long row = idx >> 8; int i = idx & 255;
    long l = row & (LL-1);
    const bf16* base = xz + row*1024 + (long)d*512;
    float xv[3], zv[3];
    #pragma unroll
    for (int k = 0; k < 3; ++k) {
        bool ok = (l + k >= 1) && (l + k <= LL);
        xv[k] = ok ? bload(base + (long)(k-1)*1024 + i)       : 0.f;
        zv[k] = ok ? bload(base + (long)(k-1)*1024 + 256 + i) : 0.f;
    }
    const float* wx = cxw + d*(II*3) + i*3;
    const float* wz = czw + d*(II*3) + i*3;
    float ax = 0.f, az = 0.f;
    #pragma unroll
    for (int k = 0; k < 3; ++k) {
        int kk = d ? (2-k) : k;
        ax = fmaf(xv[k], wx[kk], ax);
        az = fmaf(zv[k], wz[kk], az);
    }
    bstore(xbc + (long)d*MM*II + row*II + i, silu_f(ax));
    bf16* u = d ? u1 : u0;
    bstore(u + row*512 + 256 + i, silu_f(az));
}

// ---------------- proj -> delta / bt / ct per row ----------------
__global__ __launch_bounds__(256) void k_projdt(const bf16* __restrict__ xbc,
                                                const float* __restrict__ xpw,
                                                const float* __restrict__ dtw,
                                                const float* __restrict__ dtb,
                                                bf16* __restrict__ delta,
                                                float* __restrict__ btct) {
    int d = blockIdx.y;
    long row = blockIdx.x;
    __shared__ float xr[II];
    __shared__ float pr[48];
    int t = threadIdx.x;
    xr[t] = bload(xbc + (long)d*MM*II + row*II + t);
    __syncthreads();
    if (t < 48) {
        const float* w = xpw + (long)d*48*II + t*II;
        float acc = 0.f;
        for (int k = 0; k < II; ++k) acc = fmaf(w[k], xr[k], acc);
        pr[t] = acc;
    }
    __syncthreads();
    {
        const float* w = dtw + (long)d*II*32 + t*32;
        float acc = dtb[d*II + t];
        #pragma unroll
        for (int j = 0; j < 32; ++j) acc = fmaf(w[j], pr[j], acc);
        float sp = softplus_f(acc);
        bstore(delta + (long)d*MM*II + row*II + t, fminf(fmaxf(sp, 1e-4f), 1.0f));
    }
    if (t < 16) btct[(long)d*MM*16 + row*16 + t] = tanhf(pr[32 + t]);
}

// ---------------- scan pass 1 ----------------
__global__ __launch_bounds__(256) void k_scan1(const bf16* __restrict__ delta,
                                               const float* __restrict__ btct,
                                               const bf16* __restrict__ xbc,
                                               const float* __restrict__ Alog,
                                               float* __restrict__ P,
                                               float* __restrict__ Q) {
    int z = blockIdx.z;
    int d = z >> 3, b = z & 7;
    int c = blockIdx.y;
    int il = threadIdx.x >> 3, s = threadIdx.x & 7;
    int i = blockIdx.x*32 + il;
    float a = softplus_f(Alog[(long)d*II*SS + i*SS + s]) + 1e-4f;
    const bf16*  del = delta + (long)d*MM*II;
    const bf16*  xb  = xbc   + (long)d*MM*II;
    const float* bc  = btct  + (long)d*MM*16;
    float Pv = 1.f, Qv = 0.f;
    for (int tt = 0; tt < CHUNK; ++tt) {
        int t = c*CHUNK + tt;
        long l = d ? (LL-1-t) : t;
        long row = (long)b*LL + l;
        float dv  = bload(del + row*II + i);
        float btv = bc[row*16 + s];
        float xv  = bload(xb + row*II + i);
        float dec = fminf(fmaxf(expf(-dv*a), 1e-4f), 1.0f);
        Pv *= dec;
        Qv = fmaf(dec, Qv, (1.f-dec)*btv*xv);
    }
    long o = ((long)z*NCH + c)*2048 + (long)i*8 + s;
    P[o] = Pv; Q[o] = Qv;
}

// ---------------- scan pass 2 ----------------
__global__ __launch_bounds__(256) void k_scan2(const float* __restrict__ P,
                                               const float* __restrict__ Q,
                                               float* __restrict__ sinb) {
    int d = blockIdx.y;
    long idx = (long)blockIdx.x*256 + threadIdx.x;
    int b = (int)(idx >> 11); int rem = (int)(idx & 2047);
    long base = ((long)(d*8 + b)*NCH)*2048 + rem;
    float st = 0.f;
    for (int c = 0; c < NCH; ++c) {
        long o = base + (long)c*2048;
        sinb[o] = st;
        st = fmaf(P[o], st, Q[o]);
    }
}

// ---------------- scan pass 3 ----------------
__global__ __launch_bounds__(256) void k_scan3(const bf16* __restrict__ delta,
                                               const float* __restrict__ btct,
                                               const bf16* __restrict__ xbc,
                                               const float* __restrict__ Alog,
                                               const float* __restrict__ Dp,
                                               const float* __restrict__ sinb,
                                               bf16* __restrict__ u0,
                                               bf16* __restrict__ u1) {
    int z = blockIdx.z;
    int d = z >> 3, b = z & 7;
    int c = blockIdx.y;
    int il = threadIdx.x >> 3, s = threadIdx.x & 7;
    int i = blockIdx.x*32 + il;
    float a = softplus_f(Alog[(long)d*II*SS + i*SS + s]) + 1e-4f;
    float dpv = Dp[d*II + i];
    const bf16*  del = delta + (long)d*MM*II;
    const bf16*  xb  = xbc   + (long)d*MM*II;
    const float* bc  = btct  + (long)d*MM*16;
    bf16* u = d ? u1 : u0;
    float st = sinb[((long)z*NCH + c)*2048 + (long)i*8 + s];
    for (int tt = 0; tt < CHUNK; ++tt) {
        int t = c*CHUNK + tt;
        long l = d ? (LL-1-t) : t;
        long row = (long)b*LL + l;
        float dv  = bload(del + row*II + i);
        float btv = bc[row*16 + s];
        float ctv = bc[row*16 + 8 + s];
        float xv  = bload(xb + row*II + i);
        float dec = fminf(fmaxf(expf(-dv*a), 1e-4f), 1.0f);
        st = fmaf(dec, st, (1.f-dec)*btv*xv);
        float pa = st * ctv;
        pa += __shfl_xor(pa, 1);
        pa += __shfl_xor(pa, 2);
        pa += __shfl_xor(pa, 4);
        if (s == 0) bstore(u + row*512 + i, pa + dpv*xv);
    }
}

// ---------------- final LN -> f32 output ----------------
__global__ __launch_bounds__(256) void k_ln_out(const float* __restrict__ mixed,
                                                const float* __restrict__ w,
                                                const float* __restrict__ b,
                                                float* __restrict__ out) {
    __shared__ float red[10];
    long row = blockIdx.x; int t = threadIdx.x;
    float v0 = mixed[row*DDD + t], v1 = mixed[row*DDD + t + 256];
    float mean, rstd;
    block_mean_rstd(v0, v1, red, mean, rstd);
    out[row*DDD + t]       = (v0-mean)*rstd*w[t]     + b[t];
    out[row*DDD + t + 256] = (v1-mean)*rstd*w[t+256] + b[t+256];
}

extern "C" void kernel_launch(void* const* d_in, const int* in_sizes, int n_in,
                              void* d_out, int out_size, void* d_ws, size_t ws_size,
                              hipStream_t stream) {
    const float* x        = (const float*)d_in[0];
    const float* position = (const float*)d_in[1];
    const float* ln_in_w  = (const float*)d_in[2];
    const float* ln_in_b  = (const float*)d_in[3];
    const float* pos_w1   = (const float*)d_in[4];
    const float* pos_b1   = (const float*)d_in[5];
    const float* pos_w2   = (const float*)d_in[6];
    const float* pos_b2   = (const float*)d_in[7];
    const float* in_w     = (const float*)d_in[8];
    const float* cx_w     = (const float*)d_in[9];
    const float* cz_w     = (const float*)d_in[10];
    const float* xp_w     = (const float*)d_in[11];
    const float* dt_w     = (const float*)d_in[12];
    const float* dt_b     = (const float*)d_in[13];
    const float* Alog     = (const float*)d_in[14];
    const float* Dp       = (const float*)d_in[15];
    const float* out_w    = (const float*)d_in[16];
    const float* mix_w    = (const float*)d_in[17];
    const float* ln_out_w = (const float*)d_in[18];
    const float* ln_out_b = (const float*)d_in[19];
    float* out = (float*)d_out;

    char* base = (char*)d_ws;
    bf16*  si     = (bf16*)(base + WS_SI);
    bf16*  u0     = (bf16*)(base + WS_U0);
    bf16*  u1     = (bf16*)(base + WS_U1);
    bf16*  xz     = (bf16*)(base + WS_XZ);
    bf16*  posout = (bf16*)(base + WS_POS);
    bf16*  H      = (bf16*)(base + WS_H);
    float* Pb     = (float*)(base + WS_P);
    float* Qb     = (float*)(base + WS_Q);
    float* sinb   = (float*)(base + WS_SINB);
    bf16*  xbc    = (bf16*)(base + WS_XBC);
    bf16*  delta  = (bf16*)(base + WS_DELTA);
    float* btct   = (float*)(base + WS_BTCT);
    float* mixed  = (float*)(base + WS_MIXED);
    bf16*  in_wb  = (bf16*)(base + WS_INWB);
    bf16*  mix_wb = (bf16*)(base + WS_MIXWB);
    bf16*  pw2b   = (bf16*)(base + WS_PW2B);
    bf16*  owT    = (bf16*)(base + WS_OWT);
    bf16*  Wp     = (bf16*)(base + WS_WP);

    // 0. weight prep
    k_f2b<<<(524288/4+255)/256, 256, 0, stream>>>(in_w,  in_wb,  524288);
    k_f2b<<<(786432/4+255)/256, 256, 0, stream>>>(mix_w, mix_wb, 786432);
    k_f2b<<<(65536/4+255)/256, 256, 0, stream>>>(pos_w2, pw2b, 65536);
    k_tow<<<(524288+255)/256, 256, 0, stream>>>(out_w, owT);
    // W'_d = Wm_d @ ow_d  (bf16 MFMA, tiny)
    gemm_mfma<false, bf16><<<dim3(4, 4), 256, 0, stream>>>(mix_wb, 1536, owT, 512,
                                                           Wp, 512, 512);
    gemm_mfma<false, bf16><<<dim3(4, 4), 256, 0, stream>>>(mix_wb + 512, 1536,
                                                           owT + 262144, 512,
                                                           Wp + 262144, 512, 512);
    // 1. H = gelu(position @ pw1^T + pb1); posout = H @ pw2^T (MFMA)
    k_h<<<(MM*128)/256, 256, 0, stream>>>(position, pos_w1, pos_b1, H);
    gemm_mfma<false, bf16><<<dim3(4, MM/128), 256, 0, stream>>>(H, 128, pw2b, 128,
                                                                posout, 512, 128);
    // 2. si = LN(x) + posout + pb2
    k_ln_add<<<MM, 256, 0, stream>>>(x, posout, ln_in_w, ln_in_b, pos_b2, si);
    // 3. in-proj: xz = si @ in_w^T (MFMA; overwrites posout/H region)
    gemm_mfma<false, bf16><<<dim3(8, MM/128), 256, 0, stream>>>(si, 512, in_wb, 512,
                                                                xz, 1024, 512);
    // 4. conv + SiLU
    k_conv<<<dim3((MM*II)/256, 2), 256, 0, stream>>>(xz, cx_w, cz_w, xbc, u0, u1);
    // 5. proj -> delta / bt / ct
    k_projdt<<<dim3(MM, 2), 256, 0, stream>>>(xbc, xp_w, dt_w, dt_b, delta, btct);
    // 6. chunked scan
    k_scan1<<<dim3(II/32, NCH, 16), 256, 0, stream>>>(delta, btct, xbc, Alog, Pb, Qb);
    k_scan2<<<dim3(64, 2), 256, 0, stream>>>(Pb, Qb, sinb);
    k_scan3<<<dim3(II/32, NCH, 16), 256, 0, stream>>>(delta, btct, xbc, Alog, Dp,
                                                      sinb, u0, u1);
    // 7. mixed = u0@W'0^T + u1@W'1^T + si@Wm2^T  (one segmented MFMA GEMM)
    gemm_mix3<<<dim3(4, MM/128), 256, 0, stream>>>(u0, u1, si,
                                                   Wp, Wp + 262144, mix_wb + 1024, 1536,
                                                   mixed);
    // 8. out = LN(mixed) -> f32
    k_ln_out<<<MM, 256, 0, stream>>>(mixed, ln_out_w, ln_out_b, out);
}

// Round 11
// 506.145 us; speedup vs baseline: 4.9943x; 1.4711x over previous
//
#include <hip/hip_runtime.h>
#include <hip/hip_bf16.h>

typedef __hip_bfloat16 bf16;
typedef __attribute__((ext_vector_type(8))) short short8;
typedef __attribute__((ext_vector_type(4))) float floatx4;

#define BBB 8
#define LL 2048
#define DDD 512
#define II 256
#define SS 8
#define MM (BBB*LL)      // 16384 rows
#define CHUNK 32
#define NCH (LL/CHUNK)   // 64

// ---- workspace (bytes); proven ws_size >= 131,072,000 ----
#define WS_SI    0l          // si bf16 [M,512]            -> 16,777,216
#define WS_U0    16777216l   // u0 bf16 [M,512] (y0|zb0)   -> 33,554,432
#define WS_U1    33554432l   // u1 bf16 [M,512] (y1|zb1)   -> 50,331,648
#define WS_XZ    50331648l   // xz bf16 [M,1024]           -> 83,886,080
//   XZ region reuse (disjoint lifetimes):
#define WS_POS   50331648l   // posout bf16 [M,512] (early)      -> +16,777,216
#define WS_H     67108864l   // H bf16 [M,128] (early)           -> +4,194,304
#define WS_P     50331648l   // P f32 [16][64][2048] (after conv)-> +8,388,608
#define WS_Q     58720256l   // Q f32                            -> +8,388,608
#define WS_SINB  67108864l   // sinb f32                         -> +8,388,608
#define WS_XBC   83886080l   // xbc bf16 [2][M,256]        -> 100,663,296
#define WS_MIXED 83886080l   // mixed f32 [M,512] (alias xbc+delta, after scan)
#define WS_DELTA 100663296l  // delta bf16 [2][M,256]      -> 117,440,512
#define WS_BTCT  117440512l  // btct f32 [2][M,16]         -> 121,634,816
#define WS_INWB  121634816l  // in_w  bf16 [1024,512]      -> 122,683,392
#define WS_MIXWB 122683392l  // mix_w bf16 [512,1536]      -> 124,256,256
#define WS_PW2B  124256256l  // pos_w2 bf16 [512,128]      -> 124,387,328
#define WS_OWT   124387328l  // out_w^T bf16 [2][512,512]  -> 125,435,904
#define WS_WP    125435904l  // W' bf16 [2][512,512]       -> 126,484,480
#define WS_WD    126484480l  // Wd bf16 [2][256][256]      -> 126,746,624
#define WS_XPWB  126746624l  // xp_w[32:48] bf16 [2][16][256] -> 126,763,008

// ---------------- helpers ----------------
__device__ __forceinline__ float b2f(unsigned short u) {
    return __uint_as_float(((unsigned)u) << 16);
}
__device__ __forceinline__ float bload(const bf16* p) {
    return b2f(*(const unsigned short*)p);
}
__device__ __forceinline__ void bstore(bf16* p, float v) {
    *p = __float2bfloat16(v);
}
__device__ __forceinline__ float softplus_f(float x) {
    return fmaxf(x, 0.f) + log1pf(expf(-fabsf(x)));
}
__device__ __forceinline__ float silu_f(float x) {
    return x / (1.f + expf(-x));
}
__device__ __forceinline__ void block_mean_rstd(float v0, float v1, float* red,
                                                float& mean, float& rstd) {
    float s = v0 + v1, q = v0*v0 + v1*v1;
    #pragma unroll
    for (int off = 32; off > 0; off >>= 1) {
        s += __shfl_down(s, off);
        q += __shfl_down(q, off);
    }
    int w = threadIdx.x >> 6, lane = threadIdx.x & 63;
    if (lane == 0) { red[w*2] = s; red[w*2+1] = q; }
    __syncthreads();
    if (threadIdx.x == 0) {
        float ts = 0.f, tq = 0.f;
        #pragma unroll
        for (int i = 0; i < 4; ++i) { ts += red[i*2]; tq += red[i*2+1]; }
        red[8] = ts; red[9] = tq;
    }
    __syncthreads();
    float ts = red[8], tq = red[9];
    mean = ts * (1.f/DDD);
    float var = tq * (1.f/DDD) - mean*mean;
    rstd = rsqrtf(var + 1e-6f);
}

// ---------------- f32 -> bf16 conversion ----------------
__global__ __launch_bounds__(256) void k_f2b(const float* __restrict__ src,
                                             bf16* __restrict__ dst, int n) {
    int i = (blockIdx.x*256 + threadIdx.x) * 4;
    if (i >= n) return;
    float4 v = *(const float4*)(src + i);
    bf16 t[4] = {__float2bfloat16(v.x), __float2bfloat16(v.y),
                 __float2bfloat16(v.z), __float2bfloat16(v.w)};
    *(ushort4*)(dst + i) = *(ushort4*)t;
}

// ---------------- out_w transpose+convert: owT[d][k][c] = out_w[d][c][k] ----------------
__global__ __launch_bounds__(256) void k_tow(const float* __restrict__ ow,
                                             bf16* __restrict__ owT) {
    long idx = (long)blockIdx.x*256 + threadIdx.x;   // 2*512*512
    long d = idx >> 18; long rem = idx & 262143;
    long k = rem >> 9, c = rem & 511;
    bstore(owT + idx, ow[d*262144 + c*512 + k]);
}

// ---------------- Wd[d] = dt_w[d] @ xp_w[d][:32,:] -> bf16 [256,256] ----------------
__global__ __launch_bounds__(256) void k_wd(const float* __restrict__ dtw,
                                            const float* __restrict__ xpw,
                                            bf16* __restrict__ Wd) {
    int d = blockIdx.y;
    int i = blockIdx.x;                // output row 0..255
    int j = threadIdx.x;               // output col 0..255
    const float* wr = dtw + (long)d*II*32 + i*32;
    const float* xp = xpw + (long)d*48*II;
    float acc = 0.f;
    #pragma unroll
    for (int k = 0; k < 32; ++k) acc = fmaf(wr[k], xp[k*II + j], acc);
    bstore(Wd + ((long)d*II + i)*II + j, acc);
}

// ---- xpwb[d][r][k] = bf16(xp_w[d][32+r][k]), r<16 ----
__global__ __launch_bounds__(256) void k_xpw16(const float* __restrict__ xpw,
                                               bf16* __restrict__ xpwb) {
    int idx = blockIdx.x*256 + threadIdx.x;    // 2*16*256 = 8192
    int d = idx >> 12, rem = idx & 4095;
    bstore(xpwb + idx, xpw[(long)d*48*II + 32*II + rem]);
}

// ---------------- H = gelu(position @ pw1^T + pb1) -> bf16 [M,128] ----------------
__global__ __launch_bounds__(256) void k_h(const float* __restrict__ position,
                                           const float* __restrict__ pw1,
                                           const float* __restrict__ pb1,
                                           bf16* __restrict__ H) {
    long idx = (long)blockIdx.x*256 + threadIdx.x;
    long row = idx >> 7; int ph = idx & 127;
    const float* p = position + row*6;
    const float* w = pw1 + ph*6;
    float v = pb1[ph];
    #pragma unroll
    for (int j = 0; j < 6; ++j) v = fmaf(p[j], w[j], v);
    v = 0.5f * v * (1.f + erff(v * 0.70710678118654752440f));
    bstore(H + idx, v);
}

// ---------------- si = LN(x)*w+b + posout + pb2 -> bf16 ----------------
__global__ __launch_bounds__(256) void k_ln_add(const float* __restrict__ x,
                                                const bf16* __restrict__ posout,
                                                const float* __restrict__ lnw,
                                                const float* __restrict__ lnb,
                                                const float* __restrict__ pb2,
                                                bf16* __restrict__ si) {
    __shared__ float red[10];
    long row = blockIdx.x; int t = threadIdx.x;
    float v0 = x[row*DDD + t], v1 = x[row*DDD + t + 256];
    float mean, rstd;
    block_mean_rstd(v0, v1, red, mean, rstd);
    float p0 = bload(posout + row*DDD + t)       + pb2[t];
    float p1 = bload(posout + row*DDD + t + 256) + pb2[t + 256];
    bstore(si + row*DDD + t,       (v0-mean)*rstd*lnw[t]     + lnb[t]     + p0);
    bstore(si + row*DDD + t + 256, (v1-mean)*rstd*lnw[t+256] + lnb[t+256] + p1);
}

// ---------------- MFMA GEMM: C[M,N] = A[M,K] @ B^T ----------------
// EPI 0: plain store; EPI 1: v = clip(softplus(v + bias[col]),1e-4,1)
template<bool ACCUM, typename TC, int EPI = 0>
__global__ __launch_bounds__(256)
void gemm_mfma(const bf16* __restrict__ A, long lda,
               const bf16* __restrict__ B, long ldb,
               TC* __restrict__ C, long ldc, int Kdim,
               const float* __restrict__ bias = nullptr) {
    __shared__ short As[128][40];
    __shared__ short Bs[128][40];
    const int tid = threadIdx.x;
    const int lane = tid & 63;
    const int wave = tid >> 6;
    const int wm = wave >> 1, wn = wave & 1;
    const long m0 = (long)blockIdx.y * 128;
    const long n0 = (long)blockIdx.x * 128;
    const int lr = lane & 15;
    const int lq = lane >> 4;
    floatx4 acc[4][4];
    #pragma unroll
    for (int i = 0; i < 4; ++i)
        #pragma unroll
        for (int j = 0; j < 4; ++j)
            acc[i][j] = (floatx4){0.f, 0.f, 0.f, 0.f};

    for (int k0 = 0; k0 < Kdim; k0 += 32) {
        #pragma unroll
        for (int q = 0; q < 2; ++q) {
            int e = (tid + q*256) * 8;
            int r = e >> 5, c = e & 31;
            *(short8*)&As[r][c] = *(const short8*)(A + (m0+r)*lda + k0 + c);
            *(short8*)&Bs[r][c] = *(const short8*)(B + (n0+r)*ldb + k0 + c);
        }
        __syncthreads();
        short8 af[4], bfr[4];
        #pragma unroll
        for (int mi = 0; mi < 4; ++mi)
            af[mi] = *(const short8*)&As[wm*64 + mi*16 + lr][lq*8];
        #pragma unroll
        for (int ni = 0; ni < 4; ++ni)
            bfr[ni] = *(const short8*)&Bs[wn*64 + ni*16 + lr][lq*8];
        #pragma unroll
        for (int mi = 0; mi < 4; ++mi)
            #pragma unroll
            for (int ni = 0; ni < 4; ++ni)
                acc[mi][ni] = __builtin_amdgcn_mfma_f32_16x16x32_bf16(
                    af[mi], bfr[ni], acc[mi][ni], 0, 0, 0);
        __syncthreads();
    }
    #pragma unroll
    for (int mi = 0; mi < 4; ++mi)
        #pragma unroll
        for (int ni = 0; ni < 4; ++ni)
            #pragma unroll
            for (int r = 0; r < 4; ++r) {
                long row = m0 + wm*64 + mi*16 + lq*4 + r;
                long col = n0 + wn*64 + ni*16 + lr;
                float v = acc[mi][ni][r];
                if (EPI == 1)
                    v = fminf(fmaxf(softplus_f(v + bias[col]), 1e-4f), 1.0f);
                if (ACCUM) v += ((const float*)C)[row*ldc + col];
                if constexpr (sizeof(TC) == 2) bstore((bf16*)C + row*ldc + col, v);
                else ((float*)C)[row*ldc + col] = v;
            }
}

// ---------------- btct: tanh(xbc @ xpwb^T) -> f32 [2][M,16]; per-wave 16x16 tile ----------------
__global__ __launch_bounds__(256) void k_btct(const bf16* __restrict__ xbc,
                                              const bf16* __restrict__ xpwb,
                                              float* __restrict__ btct) {
    int d = blockIdx.y;
    int wave = threadIdx.x >> 6, lane = threadIdx.x & 63;
    long r0 = (long)blockIdx.x*64 + wave*16;
    int lr = lane & 15, lq = lane >> 4;
    const bf16* xb = xbc  + (long)d*MM*II;
    const bf16* wp = xpwb + (long)d*16*II;
    floatx4 acc = (floatx4){0.f, 0.f, 0.f, 0.f};
    #pragma unroll
    for (int k0 = 0; k0 < II; k0 += 32) {
        short8 af = *(const short8*)(xb + (r0 + lr)*II + k0 + lq*8);
        short8 bf = *(const short8*)(wp + lr*II + k0 + lq*8);
        acc = __builtin_amdgcn_mfma_f32_16x16x32_bf16(af, bf, acc, 0, 0, 0);
    }
    #pragma unroll
    for (int r = 0; r < 4; ++r) {
        long row = r0 + lq*4 + r;
        btct[((long)d*MM + row)*16 + lr] = tanhf(acc[r]);
    }
}

// ---------------- depthwise conv3 + SiLU ----------------
__global__ __launch_bounds__(256) void k_conv(const bf16* __restrict__ xz,
                                              const float* __restrict__ cxw,
                                              const float* __restrict__ czw,
                                              bf16* __restrict__ xbc,
                                              bf16* __restrict__ u0,
                                              bf16* __restrict__ u1) {
    int d = blockIdx.y;
    long idx = (long)blockIdx.x*256 + threadIdx.x;
    long row = idx >> 8; int i = idx & 255;
    long l = row & (LL-1);
    const bf16* base = xz + row*1024 + (long)d*512;
    float xv[3], zv[3];
    #pragma unroll
    for (int k = 0; k < 3; ++k) {
        bool ok = (l + k >= 1) && (l + k <= LL);
        xv[k] = ok ? bload(base + (long)(k-1)*1024 + i)       : 0.f;
        zv[k] = ok ? bload(base + (long)(k-1)*1024 + 256 + i) : 0.f;
    }
    const float* wx = cxw + d*(II*3) + i*3;
    const float* wz = czw + d*(II*3) + i*3;
    float ax = 0.f, az = 0.f;
    #pragma unroll
    for (int k = 0; k < 3; ++k) {
        int kk = d ? (2-k) : k;
        ax = fmaf(xv[k], wx[kk], ax);
        az = fmaf(zv[k], wz[kk], az);
    }
    bstore(xbc + (long)d*MM*II + row*II + i, silu_f(ax));
    bf16* u = d ? u1 : u0;
    bstore(u + row*512 + 256 + i, silu_f(az));
}

// ---------------- segmented MFMA GEMM: mixed = [A0|A1|A2] @ [B0|B1|B2]^T ----------------
__global__ __launch_bounds__(256)
void gemm_mix3(const bf16* __restrict__ A0, const bf16* __restrict__ A1,
               const bf16* __restrict__ A2,
               const bf16* __restrict__ B0, const bf16* __restrict__ B1,
               const bf16* __restrict__ B2, long ldb2,
               float* __restrict__ C) {
    __shared__ short As[128][40];
    __shared__ short Bs[128][40];
    const int tid = threadIdx.x;
    const int lane = tid & 63;
    const int wave = tid >> 6;
    const int wm = wave >> 1, wn = wave & 1;
    const long m0 = (long)blockIdx.y * 128;
    const long n0 = (long)blockIdx.x * 128;
    const int lr = lane & 15;
    const int lq = lane >> 4;
    floatx4 acc[4][4];
    #pragma unroll
    for (int i = 0; i < 4; ++i)
        #pragma unroll
        for (int j = 0; j < 4; ++j)
            acc[i][j] = (floatx4){0.f, 0.f, 0.f, 0.f};

    for (int k0 = 0; k0 < 1536; k0 += 32) {
        const bf16* Ap = (k0 < 512) ? A0 : (k0 < 1024 ? A1 : A2);
        const bf16* Bp = (k0 < 512) ? B0 : (k0 < 1024 ? B1 : B2);
        long ldbv = (k0 < 1024) ? 512 : ldb2;
        int kc = k0 & 511;
        #pragma unroll
        for (int q = 0; q < 2; ++q) {
            int e = (tid + q*256) * 8;
            int r = e >> 5, c = e & 31;
            *(short8*)&As[r][c] = *(const short8*)(Ap + (m0+r)*512 + kc + c);
            *(short8*)&Bs[r][c] = *(const short8*)(Bp + (n0+r)*ldbv + kc + c);
        }
        __syncthreads();
        short8 af[4], bfr[4];
        #pragma unroll
        for (int mi = 0; mi < 4; ++mi)
            af[mi] = *(const short8*)&As[wm*64 + mi*16 + lr][lq*8];
        #pragma unroll
        for (int ni = 0; ni < 4; ++ni)
            bfr[ni] = *(const short8*)&Bs[wn*64 + ni*16 + lr][lq*8];
        #pragma unroll
        for (int mi = 0; mi < 4; ++mi)
            #pragma unroll
            for (int ni = 0; ni < 4; ++ni)
                acc[mi][ni] = __builtin_amdgcn_mfma_f32_16x16x32_bf16(
                    af[mi], bfr[ni], acc[mi][ni], 0, 0, 0);
        __syncthreads();
    }
    #pragma unroll
    for (int mi = 0; mi < 4; ++mi)
        #pragma unroll
        for (int ni = 0; ni < 4; ++ni)
            #pragma unroll
            for (int r = 0; r < 4; ++r) {
                long row = m0 + wm*64 + mi*16 + lq*4 + r;
                long col = n0 + wn*64 + ni*16 + lr;
                C[row*512 + col] = acc[mi][ni][r];
            }
}

// ---------------- scan pass 1 ----------------
__global__ __launch_bounds__(256) void k_scan1(const bf16* __restrict__ delta,
                                               const float* __restrict__ btct,
                                               const bf16* __restrict__ xbc,
                                               const float* __restrict__ Alog,
                                               float* __restrict__ P,
                                               float* __restrict__ Q) {
    int z = blockIdx.z;
    int d = z >> 3, b = z & 7;
    int c = blockIdx.y;
    int il = threadIdx.x >> 3, s = threadIdx.x & 7;
    int i = blockIdx.x*32 + il;
    float a = softplus_f(Alog[(long)d*II*SS + i*SS + s]) + 1e-4f;
    const bf16*  del = delta + (long)d*MM*II;
    const bf16*  xb  = xbc   + (long)d*MM*II;
    const float* bc  = btct  + (long)d*MM*16;
    float Pv = 1.f, Qv = 0.f;
    for (int tt = 0; tt < CHUNK; ++tt) {
        int t = c*CHUNK + tt;
        long l = d ? (LL-1-t) : t;
        long row = (long)b*LL + l;
        float dv  = bload(del + row*II + i);
        float btv = bc[row*16 + s];
        float xv  = bload(xb + row*II + i);
        float dec = fminf(fmaxf(expf(-dv*a), 1e-4f), 1.0f);
        Pv *= dec;
        Qv = fmaf(dec, Qv, (1.f-dec)*btv*xv);
    }
    long o = ((long)z*NCH + c)*2048 + (long)i*8 + s;
    P[o] = Pv; Q[o] = Qv;
}

// ---------------- scan pass 2 ----------------
__global__ __launch_bounds__(256) void k_scan2(const float* __restrict__ P,
                                               const float* __restrict__ Q,
                                               float* __restrict__ sinb) {
    int d = blockIdx.y;
    long idx = (long)blockIdx.x*256 + threadIdx.x;
    int b = (int)(idx >> 11); int rem = (int)(idx & 2047);
    long base = ((long)(d*8 + b)*NCH)*2048 + rem;
    float st = 0.f;
    for (int c = 0; c < NCH; ++c) {
        long o = base + (long)c*2048;
        sinb[o] = st;
        st = fmaf(P[o], st, Q[o]);
    }
}

// ---------------- scan pass 3 ----------------
__global__ __launch_bounds__(256) void k_scan3(const bf16* __restrict__ delta,
                                               const float* __restrict__ btct,
                                               const bf16* __restrict__ xbc,
                                               const float* __restrict__ Alog,
                                               const float* __restrict__ Dp,
                                               const float* __restrict__ sinb,
                                               bf16* __restrict__ u0,
                                               bf16* __restrict__ u1) {
    int z = blockIdx.z;
    int d = z >> 3, b = z & 7;
    int c = blockIdx.y;
    int il = threadIdx.x >> 3, s = threadIdx.x & 7;
    int i = blockIdx.x*32 + il;
    float a = softplus_f(Alog[(long)d*II*SS + i*SS + s]) + 1e-4f;
    float dpv = Dp[d*II + i];
    const bf16*  del = delta + (long)d*MM*II;
    const bf16*  xb  = xbc   + (long)d*MM*II;
    const float* bc  = btct  + (long)d*MM*16;
    bf16* u = d ? u1 : u0;
    float st = sinb[((long)z*NCH + c)*2048 + (long)i*8 + s];
    for (int tt = 0; tt < CHUNK; ++tt) {
        int t = c*CHUNK + tt;
        long l = d ? (LL-1-t) : t;
        long row = (long)b*LL + l;
        float dv  = bload(del + row*II + i);
        float btv = bc[row*16 + s];
        float ctv = bc[row*16 + 8 + s];
        float xv  = bload(xb + row*II + i);
        float dec = fminf(fmaxf(expf(-dv*a), 1e-4f), 1.0f);
        st = fmaf(dec, st, (1.f-dec)*btv*xv);
        float pa = st * ctv;
        pa += __shfl_xor(pa, 1);
        pa += __shfl_xor(pa, 2);
        pa += __shfl_xor(pa, 4);
        if (s == 0) bstore(u + row*512 + i, pa + dpv*xv);
    }
}

// ---------------- final LN -> f32 output ----------------
__global__ __launch_bounds__(256) void k_ln_out(const float* __restrict__ mixed,
                                                const float* __restrict__ w,
                                                const float* __restrict__ b,
                                                float* __restrict__ out) {
    __shared__ float red[10];
    long row = blockIdx.x; int t = threadIdx.x;
    float v0 = mixed[row*DDD + t], v1 = mixed[row*DDD + t + 256];
    float mean, rstd;
    block_mean_rstd(v0, v1, red, mean, rstd);
    out[row*DDD + t]       = (v0-mean)*rstd*w[t]     + b[t];
    out[row*DDD + t + 256] = (v1-mean)*rstd*w[t+256] + b[t+256];
}

extern "C" void kernel_launch(void* const* d_in, const int* in_sizes, int n_in,
                              void* d_out, int out_size, void* d_ws, size_t ws_size,
                              hipStream_t stream) {
    const float* x        = (const float*)d_in[0];
    const float* position = (const float*)d_in[1];
    const float* ln_in_w  = (const float*)d_in[2];
    const float* ln_in_b  = (const float*)d_in[3];
    const float* pos_w1   = (const float*)d_in[4];
    const float* pos_b1   = (const float*)d_in[5];
    const float* pos_w2   = (const float*)d_in[6];
    const float* pos_b2   = (const float*)d_in[7];
    const float* in_w     = (const float*)d_in[8];
    const float* cx_w     = (const float*)d_in[9];
    const float* cz_w     = (const float*)d_in[10];
    const float* xp_w     = (const float*)d_in[11];
    const float* dt_w     = (const float*)d_in[12];
    const float* dt_b     = (const float*)d_in[13];
    const float* Alog     = (const float*)d_in[14];
    const float* Dp       = (const float*)d_in[15];
    const float* out_w    = (const float*)d_in[16];
    const float* mix_w    = (const float*)d_in[17];
    const float* ln_out_w = (const float*)d_in[18];
    const float* ln_out_b = (const float*)d_in[19];
    float* out = (float*)d_out;

    char* base = (char*)d_ws;
    bf16*  si     = (bf16*)(base + WS_SI);
    bf16*  u0     = (bf16*)(base + WS_U0);
    bf16*  u1     = (bf16*)(base + WS_U1);
    bf16*  xz     = (bf16*)(base + WS_XZ);
    bf16*  posout = (bf16*)(base + WS_POS);
    bf16*  H      = (bf16*)(base + WS_H);
    float* Pb     = (float*)(base + WS_P);
    float* Qb     = (float*)(base + WS_Q);
    float* sinb   = (float*)(base + WS_SINB);
    bf16*  xbc    = (bf16*)(base + WS_XBC);
    bf16*  delta  = (bf16*)(base + WS_DELTA);
    float* btct   = (float*)(base + WS_BTCT);
    float* mixed  = (float*)(base + WS_MIXED);
    bf16*  in_wb  = (bf16*)(base + WS_INWB);
    bf16*  mix_wb = (bf16*)(base + WS_MIXWB);
    bf16*  pw2b   = (bf16*)(base + WS_PW2B);
    bf16*  owT    = (bf16*)(base + WS_OWT);
    bf16*  Wp     = (bf16*)(base + WS_WP);
    bf16*  Wd     = (bf16*)(base + WS_WD);
    bf16*  xpwb   = (bf16*)(base + WS_XPWB);

    // 0. weight prep
    k_f2b<<<(524288/4+255)/256, 256, 0, stream>>>(in_w,  in_wb,  524288);
    k_f2b<<<(786432/4+255)/256, 256, 0, stream>>>(mix_w, mix_wb, 786432);
    k_f2b<<<(65536/4+255)/256, 256, 0, stream>>>(pos_w2, pw2b, 65536);
    k_tow<<<(524288+255)/256, 256, 0, stream>>>(out_w, owT);
    k_wd<<<dim3(256, 2), 256, 0, stream>>>(dt_w, xp_w, Wd);
    k_xpw16<<<32, 256, 0, stream>>>(xp_w, xpwb);
    gemm_mfma<false, bf16><<<dim3(4, 4), 256, 0, stream>>>(mix_wb, 1536, owT, 512,
                                                           Wp, 512, 512);
    gemm_mfma<false, bf16><<<dim3(4, 4), 256, 0, stream>>>(mix_wb + 512, 1536,
                                                           owT + 262144, 512,
                                                           Wp + 262144, 512, 512);
    // 1. pos-MLP
    k_h<<<(MM*128)/256, 256, 0, stream>>>(position, pos_w1, pos_b1, H);
    gemm_mfma<false, bf16><<<dim3(4, MM/128), 256, 0, stream>>>(H, 128, pw2b, 128,
                                                                posout, 512, 128);
    // 2. si = LN(x) + posout + pb2
    k_ln_add<<<MM, 256, 0, stream>>>(x, posout, ln_in_w, ln_in_b, pos_b2, si);
    // 3. in-proj
    gemm_mfma<false, bf16><<<dim3(8, MM/128), 256, 0, stream>>>(si, 512, in_wb, 512,
                                                                xz, 1024, 512);
    // 4. conv + SiLU
    k_conv<<<dim3((MM*II)/256, 2), 256, 0, stream>>>(xz, cx_w, cz_w, xbc, u0, u1);
    // 5a. delta[d] = clip(softplus(xbc[d] @ Wd[d]^T + dt_b[d])) (fused MFMA epilogue)
    gemm_mfma<false, bf16, 1><<<dim3(2, MM/128), 256, 0, stream>>>(
        xbc, 256, Wd, 256, delta, 256, 256, dt_b);
    gemm_mfma<false, bf16, 1><<<dim3(2, MM/128), 256, 0, stream>>>(
        xbc + (long)MM*II, 256, Wd + 65536, 256, delta + (long)MM*II, 256, 256, dt_b + 256);
    // 5b. btct = tanh(xbc @ xpwb^T)
    k_btct<<<dim3(MM/64, 2), 256, 0, stream>>>(xbc, xpwb, btct);
    // 6. chunked scan
    k_scan1<<<dim3(II/32, NCH, 16), 256, 0, stream>>>(delta, btct, xbc, Alog, Pb, Qb);
    k_scan2<<<dim3(64, 2), 256, 0, stream>>>(Pb, Qb, sinb);
    k_scan3<<<dim3(II/32, NCH, 16), 256, 0, stream>>>(delta, btct, xbc, Alog, Dp,
                                                      sinb, u0, u1);
    // 7. mixed = u0@W'0^T + u1@W'1^T + si@Wm2^T
    gemm_mix3<<<dim3(4, MM/128), 256, 0, stream>>>(u0, u1, si,
                                                   Wp, Wp + 262144, mix_wb + 1024, 1536,
                                                   mixed);
    // 8. out = LN(mixed)
    k_ln_out<<<MM, 256, 0, stream>>>(mixed, ln_out_w, ln_out_b, out);
}